// Round 13
// baseline (695.712 us; speedup 1.0000x reference)
//
#include <hip/hip_runtime.h>
#include <stdint.h>

// Koopman autoencoder — round 13 (MI355X / gfx950).
// 32-row tiles, 4 waves x 32 cols (512B/MFMA LDS traffic, half of R12),
// 8KB h-buffers -> 4-6 blocks/CU. k_decpred pins 6 mats (5 dec + comb).

typedef _Float16 h8 __attribute__((ext_vector_type(8)));
typedef _Float16 h4 __attribute__((ext_vector_type(4)));
typedef float    f4 __attribute__((ext_vector_type(4)));

#define ROWS_AUTO 104448
#define NT32      3264           // 32-row tiles
#define NUNITS    4864           // 3264 dec + 1600 pred (64 rtiles x 25 chunks)

// half-element offsets inside wt (all mats stored as W^T [n][k])
#define WT_ENCW      0
#define WT_ENCWOUT   (4*16384)
#define WT_DECW      (5*16384)
#define WT_DECWOUT   (9*16384)
#define WT_COMB      (10*16384)  // (WencI@WdecI)^T [128][128]

// ws byte offsets
#define MFULL_OFF_B 0x60000      // f16 [50][128][128] (WencI@L^{s+1}@WdecI)^T
#define ACH_OFF_B   0x200000     // f32 [50][441]
#define PE_OFF_B    0x220000     // f16 LDS-image tiles [3264][8192B]
#define PET0_OFF_B  0x1C00000    // f16 [2048][128] compact pe at t=0 (chunk-linear)

// LDS buffers (8KB each)
#define LA 0
#define LB 8192
#define LC 16384
#define LD 24576
#define LDSE (24576 + 1280)      // k_enc: LA..LC + 640 f16 biases
#define LDSD (32768 + 1280)      // k_decpred: LA..LD + 640 f16 biases

#define hsw(rl, c) ((rl)*256 + ((((c)) ^ ((rl) & 7)) << 4))

// opaque pin: forbids rematerialization/sinking of weight loads
#define PIN(B) asm volatile("" : "+v"(B[0]), "+v"(B[1]), "+v"(B[2]), "+v"(B[3]), \
                                 "+v"(B[4]), "+v"(B[5]), "+v"(B[6]), "+v"(B[7]))

__device__ __forceinline__ f4 mfma16(h8 a, h8 b, f4 c) {
  return __builtin_amdgcn_mfma_f32_16x16x32_f16(a, b, c, 0, 0, 0);
}
__device__ __forceinline__ h8 cvt8(f4 a, f4 b) {
  h8 r;
  r[0]=(_Float16)a[0]; r[1]=(_Float16)a[1]; r[2]=(_Float16)a[2]; r[3]=(_Float16)a[3];
  r[4]=(_Float16)b[0]; r[5]=(_Float16)b[1]; r[6]=(_Float16)b[2]; r[7]=(_Float16)b[3];
  return r;
}
// wave's 32-col slice of a 128x128 W^T
__device__ __forceinline__ void loadW(h8 B[8], const _Float16* gW, int nbase, int r15, int hi) {
#pragma unroll
  for (int nt = 0; nt < 2; ++nt)
#pragma unroll
    for (int ks = 0; ks < 4; ++ks)
      B[nt*4+ks] = *(const h8*)(gW + (size_t)(nbase + nt*16 + r15)*128 + ks*32 + hi*8);
}

// SWAPPED operands, 32 rows: lane holds out[row=rt*16+r15][n=wbase+nt*16+hi*4+d]
__device__ __forceinline__ void mm(const char* sm, int hb, const h8 B[8],
                                   f4 acc[2][2], int r15, int hi) {
#pragma unroll
  for (int rt = 0; rt < 2; ++rt) { acc[rt][0] = (f4){0,0,0,0}; acc[rt][1] = (f4){0,0,0,0}; }
#pragma unroll
  for (int ks = 0; ks < 4; ++ks) {
    int c = ks*4 + hi;
    h8 a0 = *(const h8*)(sm + hb + hsw(r15, c));
    h8 a1 = *(const h8*)(sm + hb + hsw(16 + r15, c));
    acc[0][0] = mfma16(B[ks],   a0, acc[0][0]);
    acc[0][1] = mfma16(B[4+ks], a0, acc[0][1]);
    acc[1][0] = mfma16(B[ks],   a1, acc[1][0]);
    acc[1][1] = mfma16(B[4+ks], a1, acc[1][1]);
  }
}

// ReLU(acc + f16 bias) -> h[hb]
__device__ __forceinline__ void hws(char* sm, int hb, int wbase, const f4 acc[2][2],
                                    const _Float16* blh, int bo, int r15, int hi) {
  h4 b0 = *(const h4*)(blh + bo + wbase + hi*4);
  h4 b1 = *(const h4*)(blh + bo + wbase + 16 + hi*4);
  int bo2 = (hi & 1) * 8;
#pragma unroll
  for (int nt = 0; nt < 2; ++nt) {
    int c = ((wbase + nt*16) >> 3) + (hi >> 1);
    h4 bb = nt ? b1 : b0;
#pragma unroll
    for (int rt = 0; rt < 2; ++rt) {
      int row = rt*16 + r15;
      h4 p;
#pragma unroll
      for (int d = 0; d < 4; ++d) p[d] = (_Float16)fmaxf(acc[rt][nt][d] + (float)bb[d], 0.f);
      *(h4*)(sm + hb + row*256 + ((c ^ (row & 7)) << 4) + bo2) = p;
    }
  }
}
// raw acc -> h[hb]
__device__ __forceinline__ void hwa(char* sm, int hb, int wbase, const f4 acc[2][2],
                                    int r15, int hi) {
  int bo2 = (hi & 1) * 8;
#pragma unroll
  for (int nt = 0; nt < 2; ++nt) {
    int c = ((wbase + nt*16) >> 3) + (hi >> 1);
#pragma unroll
    for (int rt = 0; rt < 2; ++rt) {
      int row = rt*16 + r15;
      h4 p;
#pragma unroll
      for (int d = 0; d < 4; ++d) p[d] = (_Float16)acc[rt][nt][d];
      *(h4*)(sm + hb + row*256 + ((c ^ (row & 7)) << 4) + bo2) = p;
    }
  }
}

// out = acc + bout + skip(LDS hskip) -> f32 trbuf (16KB at trb) -> global full lines
__device__ __forceinline__ void epi(char* sm, int hskip, int trb, int wbase,
                                    const f4 acc[2][2], const _Float16* blh, int bout,
                                    float* dst, int rstride, int tid, int r15, int hi) {
  h4 b0 = *(const h4*)(blh + bout + wbase + hi*4);
  h4 b1 = *(const h4*)(blh + bout + wbase + 16 + hi*4);
  int bo2 = (hi & 1) * 8;
#pragma unroll
  for (int nt = 0; nt < 2; ++nt) {
    int c = ((wbase + nt*16) >> 3) + (hi >> 1);
    int q = (wbase >> 2) + nt*4 + hi;
    h4 bb = nt ? b1 : b0;
#pragma unroll
    for (int rt = 0; rt < 2; ++rt) {
      int row = rt*16 + r15;
      h4 sk = *(const h4*)(sm + hskip + row*256 + ((c ^ (row & 7)) << 4) + bo2);
      f4 v;
#pragma unroll
      for (int d = 0; d < 4; ++d) v[d] = acc[rt][nt][d] + (float)bb[d] + (float)sk[d];
      *(f4*)(sm + trb + row*512 + ((q ^ ((row & 7) << 2)) << 4)) = v;
    }
  }
  __syncthreads();
#pragma unroll
  for (int i = 0; i < 4; ++i) {
    int idx = i*256 + tid, row = idx >> 5, qq = idx & 31;
    f4 v = *(const f4*)(sm + trb + row*512 + ((qq ^ ((row & 7) << 2)) << 4));
    *(f4*)(dst + (size_t)row*rstride + qq*4) = v;
  }
}

#define LAYR(LIN, LOUT, BW, BO) do {                       \
    mm(sm, LIN, BW, acc, r15, hi);                         \
    hws(sm, LOUT, wbase, acc, blh, BO, r15, hi);           \
    __syncthreads();                                       \
  } while (0)

// ---------------- prep kernels ----------------

__global__ __launch_bounds__(512) void k_prep(
    const float* __restrict__ encW, const float* __restrict__ encWout,
    const float* __restrict__ decW, const float* __restrict__ decWout,
    const float* __restrict__ L,
    _Float16* __restrict__ wt, float* __restrict__ ach) {
  __shared__ float chA[441], chB[441];
  int m = blockIdx.y, tid = threadIdx.x;
  if (m == 10) {
    if (blockIdx.x != 0) return;
    if (tid < 441) chA[tid] = L[tid];
    __syncthreads();
    for (int s = 0; s < 50; ++s) {
      if (tid < 441) ach[s*441 + tid] = chA[tid];
      if (s == 49) break;
      if (tid < 441) {
        int i = tid / 21, j = tid % 21; float a = 0.f;
        for (int k = 0; k < 21; ++k) a += chA[i*21 + k] * L[k*21 + j];
        chB[tid] = a;
      }
      __syncthreads();
      if (tid < 441) chA[tid] = chB[tid];
      __syncthreads();
    }
    return;
  }
  int idx = blockIdx.x*512 + tid;
  if (idx >= 16384) return;
  const float* src; _Float16* dst;
  if (m < 4)       { src = encW + m*16384;     dst = wt + WT_ENCW + m*16384; }
  else if (m == 4) { src = encWout;            dst = wt + WT_ENCWOUT; }
  else if (m < 9)  { src = decW + (m-5)*16384; dst = wt + WT_DECW + (m-5)*16384; }
  else             { src = decWout;            dst = wt + WT_DECWOUT; }
  int n = idx >> 7, k = idx & 127;
  dst[idx] = (_Float16)src[k*128 + n];            // W^T[n][k]
}

__global__ __launch_bounds__(512) void k_aux(
    const float* __restrict__ ach, const float* __restrict__ wencI,
    const float* __restrict__ wdecI,
    _Float16* __restrict__ mfull, _Float16* __restrict__ wt) {
  __shared__ float T1[2688];
  __shared__ float sa[441];
  int s = blockIdx.x, t = threadIdx.x;
  if (s < 50) {
    if (t < 441) sa[t] = ach[s*441 + t];
    __syncthreads();
    for (int idx = t; idx < 2688; idx += 512) {
      int k = idx / 21, j = idx % 21;
      float a = 0.f;
      for (int u = 0; u < 21; ++u) a += wencI[k*21 + u] * sa[u*21 + j];
      T1[idx] = a;
    }
  } else {
    for (int idx = t; idx < 2688; idx += 512) T1[idx] = wencI[idx];
  }
  __syncthreads();
  _Float16* dst = (s < 50) ? (mfull + (size_t)s*16384) : (wt + WT_COMB);
  for (int idx = t; idx < 16384; idx += 512) {    // M^T[n][k]
    int n = idx >> 7, k = idx & 127;
    float a = 0.f;
    for (int j = 0; j < 21; ++j) a += T1[k*21 + j] * wdecI[j*128 + n];
    dst[idx] = (_Float16)a;
  }
}

// ---------------- encoder: x -> pe image + compact pet0 ----------------

__global__ __launch_bounds__(256, 6) void k_enc(
    const float* __restrict__ x, const _Float16* __restrict__ wt,
    const float* __restrict__ enc_b, const float* __restrict__ enc_bout,
    _Float16* __restrict__ pe_ws, _Float16* __restrict__ pet0) {
  __shared__ char sm[LDSE];
  _Float16* blh = (_Float16*)(sm + 24576);
  int tid = threadIdx.x, lane = tid & 63;
  int r15 = lane & 15, hi = lane >> 4;
  int wbase = (tid >> 6) * 32;
  h8 B0[8], B1[8], B2[8], B3[8], B4[8];
  loadW(B0, wt + WT_ENCW,           wbase, r15, hi);
  loadW(B1, wt + WT_ENCW + 16384,   wbase, r15, hi);
  loadW(B2, wt + WT_ENCW + 2*16384, wbase, r15, hi);
  loadW(B3, wt + WT_ENCW + 3*16384, wbase, r15, hi);
  loadW(B4, wt + WT_ENCWOUT,        wbase, r15, hi);
  PIN(B0); PIN(B1); PIN(B2); PIN(B3); PIN(B4);
  for (int i = tid; i < 640; i += 256)
    blh[i] = (_Float16)(i < 512 ? enc_b[i] : enc_bout[i - 512]);
  f4 acc[2][2];

  for (int t = blockIdx.x; t < NT32; t += gridDim.x) {
    size_t rb = (size_t)t * 32;
#pragma unroll
    for (int i = 0; i < 2; ++i) {                 // stage x -> LA (enc skip)
      int idx = i*256 + tid, rl = idx >> 4, c = idx & 15;
      const float* s = x + (rb + rl)*128 + c*8;
      f4 v0 = *(const f4*)s, v1 = *(const f4*)(s + 4);
      *(h8*)(sm + LA + hsw(rl, c)) = cvt8(v0, v1);
    }
    __syncthreads();
    LAYR(LA, LB, B0, 0); LAYR(LB, LC, B1, 128);
    LAYR(LC, LB, B2, 256); LAYR(LB, LC, B3, 384);
    mm(sm, LC, B4, acc, r15, hi);                 // encWout
    {                                             // pe = acc + bout + x, in-place LA
      h4 bb0 = *(const h4*)(blh + 512 + wbase + hi*4);
      h4 bb1 = *(const h4*)(blh + 512 + wbase + 16 + hi*4);
      int bo2 = (hi & 1) * 8;
#pragma unroll
      for (int nt = 0; nt < 2; ++nt) {
        int c = ((wbase + nt*16) >> 3) + (hi >> 1);
        h4 bb = nt ? bb1 : bb0;
#pragma unroll
        for (int rt = 0; rt < 2; ++rt) {
          int row = rt*16 + r15;
          int soff = LA + row*256 + ((c ^ (row & 7)) << 4) + bo2;
          h4 sk = *(const h4*)(sm + soff);
          h4 p;
#pragma unroll
          for (int d = 0; d < 4; ++d) p[d] = (_Float16)(acc[rt][nt][d] + (float)bb[d] + (float)sk[d]);
          *(h4*)(sm + soff) = p;                  // lane-private slot: no race
        }
      }
    }
    __syncthreads();
    {                                             // dump pe image + compact pet0
      char* g = (char*)(pe_ws) + (size_t)t*8192;
#pragma unroll
      for (int i = 0; i < 2; ++i) {
        int idx = i*256 + tid, off = idx*16;
        f4 v = *(const f4*)(sm + LA + off);
        *(f4*)(g + off) = v;
        int rl = idx >> 4, slot = idx & 15;
        size_t rg = rb + (size_t)rl;
        if (rg % 51u == 0u) {
          int c = slot ^ (rl & 7);                // unswizzle -> chunk-linear
          *(f4*)((char*)pet0 + (rg/51u)*256 + c*16) = v;
        }
      }
    }
    __syncthreads();                              // dump reads done before next tile
  }
}

// ---------------- dec tiles + pred units ----------------

__global__ __launch_bounds__(256, 4) void k_decpred(
    const _Float16* __restrict__ wt, const _Float16* __restrict__ pe_ws,
    const _Float16* __restrict__ pet0, const _Float16* __restrict__ mfull,
    const float* __restrict__ dec_b, const float* __restrict__ dec_bout,
    float* __restrict__ out1, float* __restrict__ out2, float* __restrict__ out3) {
  __shared__ char sm[LDSD];
  _Float16* blh = (_Float16*)(sm + 32768);
  int tid = threadIdx.x, lane = tid & 63;
  int r15 = lane & 15, hi = lane >> 4;
  int wbase = (tid >> 6) * 32;
  h8 B0[8], B1[8], B2[8], B3[8], B4[8], B5[8];
  loadW(B0, wt + WT_DECW,           wbase, r15, hi);
  loadW(B1, wt + WT_DECW + 16384,   wbase, r15, hi);
  loadW(B2, wt + WT_DECW + 2*16384, wbase, r15, hi);
  loadW(B3, wt + WT_DECW + 3*16384, wbase, r15, hi);
  loadW(B4, wt + WT_DECWOUT,        wbase, r15, hi);
  loadW(B5, wt + WT_COMB,           wbase, r15, hi);
  PIN(B0); PIN(B1); PIN(B2); PIN(B3); PIN(B4); PIN(B5);
  for (int i = tid; i < 640; i += 256)
    blh[i] = (_Float16)(i < 512 ? dec_b[i] : dec_bout[i - 512]);
  f4 acc[2][2];

  for (int u = blockIdx.x; u < NUNITS; u += gridDim.x) {
    __syncthreads();                              // protect bufs across units
    if (u < NT32) {
      // ---------- dec tile: pe -> out2 ; pd = pe@comb -> dec -> out1 ----------
      const char* src = (const char*)pe_ws + (size_t)u*8192;
#pragma unroll
      for (int i = 0; i < 2; ++i) {               // stage pe -> LA (input+skip)
        int off = (i*256 + tid)*16;
        *(f4*)(sm + LA + off) = *(const f4*)(src + off);
      }
      __syncthreads();
      // stream B: dec(pe)
      LAYR(LA, LB, B0, 0); LAYR(LB, LC, B1, 128);
      LAYR(LC, LB, B2, 256); LAYR(LB, LC, B3, 384);
      mm(sm, LC, B4, acc, r15, hi);               // decWout
      __syncthreads();                            // LB/LC reads done -> trbuf safe
      epi(sm, LA, LB, wbase, acc, blh, 512,
          out2 + (size_t)u*32*128, 128, tid, r15, hi);
      mm(sm, LA, B5, acc, r15, hi);               // pd = pe @ comb
      hwa(sm, LD, wbase, acc, r15, hi);           // pd -> LD (input+skip)
      __syncthreads();
      // stream A: dec(pd)
      LAYR(LD, LA, B0, 0); LAYR(LA, LB, B1, 128);
      LAYR(LB, LC, B2, 256); LAYR(LC, LA, B3, 384);
      mm(sm, LA, B4, acc, r15, hi);               // decWout
      __syncthreads();                            // LA/LB/LC reads done -> trbuf safe
      epi(sm, LD, LB, wbase, acc, blh, 512,
          out1 + (size_t)u*32*128, 128, tid, r15, hi);
    } else {
      // ---------- pred unit: pet0 rtile x 2 Koopman steps ----------
      int p = u - NT32, rtile = p / 25, chunk = p % 25;
#pragma unroll
      for (int i = 0; i < 2; ++i) {               // stage pet0 -> LA (persistent)
        int idx = i*256 + tid, rl = idx >> 4, c = idx & 15;
        f4 v = *(const f4*)((const char*)pet0 + (size_t)(rtile*32 + rl)*256 + c*16);
        *(f4*)(sm + LA + hsw(rl, c)) = v;
      }
      __syncthreads();
      for (int s = chunk*2; s < chunk*2 + 2; ++s) {
        {
          h8 Bm[8];
          loadW(Bm, mfull + (size_t)s*16384, wbase, r15, hi);
          mm(sm, LA, Bm, acc, r15, hi);           // di = pet0 @ Mfull_s
        }
        hwa(sm, LB, wbase, acc, r15, hi);         // di -> LB (input+skip)
        __syncthreads();
        LAYR(LB, LC, B0, 0); LAYR(LC, LD, B1, 128);
        LAYR(LD, LC, B2, 256); LAYR(LC, LD, B3, 384);
        mm(sm, LD, B4, acc, r15, hi);             // decWout
        __syncthreads();                          // LC/LD reads done -> trbuf safe
        epi(sm, LB, LC, wbase, acc, blh, 512,
            out3 + ((size_t)rtile*32*50 + s)*128, 50*128, tid, r15, hi);
        __syncthreads();                          // trbuf/skip reads done before next s
      }
    }
  }
}

// ---------------- launch ----------------

extern "C" void kernel_launch(void* const* d_in, const int* in_sizes, int n_in,
                              void* d_out, int out_size, void* d_ws, size_t ws_size,
                              hipStream_t stream) {
  const float* x        = (const float*)d_in[0];
  const float* encW     = (const float*)d_in[1];
  const float* enc_b    = (const float*)d_in[2];
  const float* encWout  = (const float*)d_in[3];
  const float* enc_bout = (const float*)d_in[4];
  const float* decW     = (const float*)d_in[5];
  const float* dec_b    = (const float*)d_in[6];
  const float* decWout  = (const float*)d_in[7];
  const float* dec_bout = (const float*)d_in[8];
  const float* wencI    = (const float*)d_in[9];
  const float* L        = (const float*)d_in[10];
  const float* wdecI    = (const float*)d_in[11];

  char* ws = (char*)d_ws;
  _Float16* wt    = (_Float16*)ws;
  _Float16* mfull = (_Float16*)(ws + MFULL_OFF_B);
  float*    ach   = (float*)(ws + ACH_OFF_B);
  _Float16* pe_ws = (_Float16*)(ws + PE_OFF_B);
  _Float16* pet0  = (_Float16*)(ws + PET0_OFF_B);

  float* out1 = (float*)d_out;                       // autoencoder_output
  float* out2 = out1 + (size_t)ROWS_AUTO*128;        // outer_auto_output
  float* out3 = out2 + (size_t)ROWS_AUTO*128;        // predictions [2048][50][128]

  hipLaunchKernelGGL(k_prep, dim3(32, 11), dim3(512), 0, stream,
                     encW, encWout, decW, decWout, L, wt, ach);
  hipLaunchKernelGGL(k_aux, dim3(51), dim3(512), 0, stream,
                     ach, wencI, wdecI, mfull, wt);
  hipLaunchKernelGGL(k_enc, dim3(1536), dim3(256), 0, stream,
                     x, wt, enc_b, enc_bout, pe_ws, pet0);
  hipLaunchKernelGGL(k_decpred, dim3(1024), dim3(256), 0, stream,
                     wt, pe_ws, pet0, mfull, dec_b, dec_bout, out1, out2, out3);
}

// Round 14
// 199.286 us; speedup vs baseline: 3.4910x; 3.4910x over previous
//
#include <hip/hip_runtime.h>
#include <stdint.h>

// Koopman autoencoder — round 14 (MI355X / gfx950).
// R9 base (best verified) + direct f4 global stores from acc fragments
// (no f32 trbuf round-trip: -6 barriers/dec-tile, -4/pred-step).
// 5 pinned mats, launch_bounds(256,2) (cap 256 regs >= 160 pin + acc).

typedef _Float16 h8 __attribute__((ext_vector_type(8)));
typedef _Float16 h4 __attribute__((ext_vector_type(4)));
typedef float    f4 __attribute__((ext_vector_type(4)));

#define ROWS_AUTO 104448
#define NT64      1632           // 64-row dec tiles
#define NUNITS    2432           // 1632 dec + 800 pred (32 rtiles x 25 chunks x 2 steps)

// half-element offsets inside wt (all mats stored as W^T [n][k])
#define WT_ENCW      0
#define WT_ENCWOUT   (4*16384)
#define WT_DECW      (5*16384)
#define WT_DECWOUT   (9*16384)
#define WT_COMB      (10*16384)  // (WencI@WdecI)^T [128][128]

// ws byte offsets
#define MFULL_OFF_B 0x60000      // f16 [50][128][128] (WencI@L^{s+1}@WdecI)^T
#define ACH_OFF_B   0x200000     // f32 [50][441]
#define PE_OFF_B    0x220000     // f16 LDS-image tiles [1632][16384B]
#define PET0_OFF_B  0x1C00000    // f16 [2048][128] compact pe at t=0 (chunk-linear)

// LDS buffers (16KB each)
#define H0 0
#define H1 16384
#define H2 32768
#define H3 49152
#define LDSE (49152 + 2560)      // k_enc: H0..H2 + 640 f32 biases
#define LDSD (65536 + 2560)      // k_decpred: H0..H3 + 640 f32 biases

#define hsw(rl, c) ((rl)*256 + ((((c)) ^ ((rl) & 7)) << 4))

// opaque pin: forbids rematerialization/sinking of weight loads into the loop
#define PIN(B) asm volatile("" : "+v"(B[0]), "+v"(B[1]), "+v"(B[2]), "+v"(B[3]), \
                                 "+v"(B[4]), "+v"(B[5]), "+v"(B[6]), "+v"(B[7]))

__device__ __forceinline__ f4 mfma16(h8 a, h8 b, f4 c) {
  return __builtin_amdgcn_mfma_f32_16x16x32_f16(a, b, c, 0, 0, 0);
}
__device__ __forceinline__ h8 cvt8(f4 a, f4 b) {
  h8 r;
  r[0]=(_Float16)a[0]; r[1]=(_Float16)a[1]; r[2]=(_Float16)a[2]; r[3]=(_Float16)a[3];
  r[4]=(_Float16)b[0]; r[5]=(_Float16)b[1]; r[6]=(_Float16)b[2]; r[7]=(_Float16)b[3];
  return r;
}
// wave's 32-col slice of a 128x128 W^T
__device__ __forceinline__ void loadW(h8 B[8], const _Float16* gW, int nbase, int r15, int hi) {
#pragma unroll
  for (int nt = 0; nt < 2; ++nt)
#pragma unroll
    for (int ks = 0; ks < 4; ++ks)
      B[nt*4+ks] = *(const h8*)(gW + (size_t)(nbase + nt*16 + r15)*128 + ks*32 + hi*8);
}

// SWAPPED operands: lane holds out[row=rt*16+r15][n=wbase+nt*16+hi*4+d]
__device__ __forceinline__ void mmF4s(const char* sm, int hb, const h8 B[8],
                                      f4 acc[4][2], int r15, int hi) {
#pragma unroll
  for (int rt = 0; rt < 4; ++rt) { acc[rt][0] = (f4){0,0,0,0}; acc[rt][1] = (f4){0,0,0,0}; }
#pragma unroll
  for (int ks = 0; ks < 4; ++ks) {
    int c = ks*4 + hi;
    h8 a[4];
#pragma unroll
    for (int rt = 0; rt < 4; ++rt) a[rt] = *(const h8*)(sm + hb + hsw(rt*16 + r15, c));
#pragma unroll
    for (int rt = 0; rt < 4; ++rt) {
      acc[rt][0] = mfma16(B[ks],   a[rt], acc[rt][0]);
      acc[rt][1] = mfma16(B[4+ks], a[rt], acc[rt][1]);
    }
  }
}

// ReLU(acc + bias) -> h[hb] via b64 writes
__device__ __forceinline__ void hw4s(char* sm, int hb, int wbase, const f4 acc[4][2],
                                     const float* bl, int bo, int r15, int hi) {
  f4 bb0 = *(const f4*)(bl + bo + wbase + hi*4);
  f4 bb1 = *(const f4*)(bl + bo + wbase + 16 + hi*4);
  int bo2 = (hi & 1) * 8;
#pragma unroll
  for (int nt = 0; nt < 2; ++nt) {
    int c = ((wbase + nt*16) >> 3) + (hi >> 1);
    f4 bb = nt ? bb1 : bb0;
#pragma unroll
    for (int rt = 0; rt < 4; ++rt) {
      int row = rt*16 + r15;
      h4 p;
#pragma unroll
      for (int d = 0; d < 4; ++d) p[d] = (_Float16)fmaxf(acc[rt][nt][d] + bb[d], 0.f);
      *(h4*)(sm + hb + row*256 + ((c ^ (row & 7)) << 4) + bo2) = p;
    }
  }
}
// raw acc -> h[hb] (no bias/relu)
__device__ __forceinline__ void hw4r(char* sm, int hb, int wbase, const f4 acc[4][2],
                                     int r15, int hi) {
  int bo2 = (hi & 1) * 8;
#pragma unroll
  for (int nt = 0; nt < 2; ++nt) {
    int c = ((wbase + nt*16) >> 3) + (hi >> 1);
#pragma unroll
    for (int rt = 0; rt < 4; ++rt) {
      int row = rt*16 + r15;
      h4 p;
#pragma unroll
      for (int d = 0; d < 4; ++d) p[d] = (_Float16)acc[rt][nt][d];
      *(h4*)(sm + hb + row*256 + ((c ^ (row & 7)) << 4) + bo2) = p;
    }
  }
}

// DIRECT epilogue: out = acc + bout + skip(LDS hskip, lane-private slot) -> f4 global.
// 64 lanes/instr: 16 rows x 64B contiguous segments (full sectors, plain stores).
// No LDS writes, no barriers.
__device__ __forceinline__ void epi_direct(const char* sm, int hskip, int wbase,
                                           const f4 acc[4][2], const float* bl,
                                           float* dst, int rstride, int r15, int hi) {
  f4 bb0 = *(const f4*)(bl + 512 + wbase + hi*4);
  f4 bb1 = *(const f4*)(bl + 512 + wbase + 16 + hi*4);
  int bo2 = (hi & 1) * 8;
#pragma unroll
  for (int nt = 0; nt < 2; ++nt) {
    int c = ((wbase + nt*16) >> 3) + (hi >> 1);
    int n0 = wbase + nt*16 + hi*4;
    f4 bb = nt ? bb1 : bb0;
#pragma unroll
    for (int rt = 0; rt < 4; ++rt) {
      int row = rt*16 + r15;
      h4 sk = *(const h4*)(sm + hskip + row*256 + ((c ^ (row & 7)) << 4) + bo2);
      f4 v;
#pragma unroll
      for (int d = 0; d < 4; ++d) v[d] = acc[rt][nt][d] + bb[d] + (float)sk[d];
      *(f4*)(dst + (size_t)row*rstride + n0) = v;
    }
  }
}

#define LAYD(HIN, HOUT, BW, BO) do {                                 \
    mmF4s(sm, HIN, BW, acc, r15, hi);                                \
    hw4s(sm, HOUT, wbase, acc, bl, BO, r15, hi);                     \
    __syncthreads();                                                 \
  } while (0)

// ---------------- prep kernels ----------------

__global__ __launch_bounds__(512) void k_prep(
    const float* __restrict__ encW, const float* __restrict__ encWout,
    const float* __restrict__ decW, const float* __restrict__ decWout,
    const float* __restrict__ L,
    _Float16* __restrict__ wt, float* __restrict__ ach) {
  __shared__ float chA[441], chB[441];
  int m = blockIdx.y, tid = threadIdx.x;
  if (m == 10) {
    if (blockIdx.x != 0) return;
    if (tid < 441) chA[tid] = L[tid];
    __syncthreads();
    for (int s = 0; s < 50; ++s) {
      if (tid < 441) ach[s*441 + tid] = chA[tid];
      if (s == 49) break;
      if (tid < 441) {
        int i = tid / 21, j = tid % 21; float a = 0.f;
        for (int k = 0; k < 21; ++k) a += chA[i*21 + k] * L[k*21 + j];
        chB[tid] = a;
      }
      __syncthreads();
      if (tid < 441) chA[tid] = chB[tid];
      __syncthreads();
    }
    return;
  }
  int idx = blockIdx.x*512 + tid;
  if (idx >= 16384) return;
  const float* src; _Float16* dst;
  if (m < 4)       { src = encW + m*16384;     dst = wt + WT_ENCW + m*16384; }
  else if (m == 4) { src = encWout;            dst = wt + WT_ENCWOUT; }
  else if (m < 9)  { src = decW + (m-5)*16384; dst = wt + WT_DECW + (m-5)*16384; }
  else             { src = decWout;            dst = wt + WT_DECWOUT; }
  int n = idx >> 7, k = idx & 127;
  dst[idx] = (_Float16)src[k*128 + n];            // W^T[n][k]
}

__global__ __launch_bounds__(512) void k_aux(
    const float* __restrict__ ach, const float* __restrict__ wencI,
    const float* __restrict__ wdecI,
    _Float16* __restrict__ mfull, _Float16* __restrict__ wt) {
  __shared__ float T1[2688];
  __shared__ float sa[441];
  int s = blockIdx.x, t = threadIdx.x;
  if (s < 50) {
    if (t < 441) sa[t] = ach[s*441 + t];
    __syncthreads();
    for (int idx = t; idx < 2688; idx += 512) {
      int k = idx / 21, j = idx % 21;
      float a = 0.f;
      for (int u = 0; u < 21; ++u) a += wencI[k*21 + u] * sa[u*21 + j];
      T1[idx] = a;
    }
  } else {
    for (int idx = t; idx < 2688; idx += 512) T1[idx] = wencI[idx];
  }
  __syncthreads();
  _Float16* dst = (s < 50) ? (mfull + (size_t)s*16384) : (wt + WT_COMB);
  for (int idx = t; idx < 16384; idx += 512) {    // M^T[n][k]
    int n = idx >> 7, k = idx & 127;
    float a = 0.f;
    for (int j = 0; j < 21; ++j) a += T1[k*21 + j] * wdecI[j*128 + n];
    dst[idx] = (_Float16)a;
  }
}

// ---------------- encoder: x -> pe image + compact pet0 (R9-exact) ----------------

__global__ __launch_bounds__(256, 2) void k_enc(
    const float* __restrict__ x, const _Float16* __restrict__ wt,
    const float* __restrict__ enc_b, const float* __restrict__ enc_bout,
    _Float16* __restrict__ pe_ws, _Float16* __restrict__ pet0) {
  __shared__ char sm[LDSE];
  float* bl = (float*)(sm + 49152);
  int tid = threadIdx.x, lane = tid & 63;
  int r15 = lane & 15, hi = lane >> 4;
  int wbase = (tid >> 6) * 32;
  h8 B0[8], B1[8], B2[8], B3[8], B4[8];
  loadW(B0, wt + WT_ENCW,           wbase, r15, hi);
  loadW(B1, wt + WT_ENCW + 16384,   wbase, r15, hi);
  loadW(B2, wt + WT_ENCW + 2*16384, wbase, r15, hi);
  loadW(B3, wt + WT_ENCW + 3*16384, wbase, r15, hi);
  loadW(B4, wt + WT_ENCWOUT,        wbase, r15, hi);
  PIN(B0); PIN(B1); PIN(B2); PIN(B3); PIN(B4);
  bl[tid] = enc_b[tid]; bl[256 + tid] = enc_b[256 + tid];
  if (tid < 128) bl[512 + tid] = enc_bout[tid];
  f4 acc[4][2];

  for (int t = blockIdx.x; t < NT64; t += gridDim.x) {
    size_t rb = (size_t)t * 64;
#pragma unroll
    for (int i = 0; i < 4; ++i) {                 // stage x -> H0 (enc skip)
      int idx = i*256 + tid, rl = idx >> 4, c = idx & 15;
      const float* s = x + (rb + rl)*128 + c*8;
      f4 v0 = *(const f4*)s, v1 = *(const f4*)(s + 4);
      *(h8*)(sm + H0 + hsw(rl, c)) = cvt8(v0, v1);
    }
    __syncthreads();
    LAYD(H0, H1, B0, 0); LAYD(H1, H2, B1, 128);
    LAYD(H2, H1, B2, 256); LAYD(H1, H2, B3, 384);
    mmF4s(sm, H2, B4, acc, r15, hi);              // encWout
    {                                             // pe = acc + bout + x, in-place H0
      f4 bb0 = *(const f4*)(bl + 512 + wbase + hi*4);
      f4 bb1 = *(const f4*)(bl + 512 + wbase + 16 + hi*4);
      int bo2 = (hi & 1) * 8;
#pragma unroll
      for (int nt = 0; nt < 2; ++nt) {
        int c = ((wbase + nt*16) >> 3) + (hi >> 1);
        f4 bb = nt ? bb1 : bb0;
#pragma unroll
        for (int rt = 0; rt < 4; ++rt) {
          int row = rt*16 + r15;
          int soff = H0 + row*256 + ((c ^ (row & 7)) << 4) + bo2;
          h4 sk = *(const h4*)(sm + soff);
          h4 p;
#pragma unroll
          for (int d = 0; d < 4; ++d) p[d] = (_Float16)(acc[rt][nt][d] + bb[d] + (float)sk[d]);
          *(h4*)(sm + soff) = p;                  // lane-private slot: no race
        }
      }
    }
    __syncthreads();
    {                                             // dump pe image + compact pet0
      char* g = (char*)(pe_ws) + (size_t)t*16384;
#pragma unroll
      for (int i = 0; i < 4; ++i) {
        int idx = i*256 + tid, off = idx*16;
        f4 v = *(const f4*)(sm + H0 + off);
        *(f4*)(g + off) = v;
        int rl = idx >> 4, slot = idx & 15;
        size_t rg = rb + (size_t)rl;
        if (rg % 51u == 0u) {
          int c = slot ^ (rl & 7);                // unswizzle -> chunk-linear
          *(f4*)((char*)pet0 + (rg/51u)*256 + c*16) = v;
        }
      }
    }
    __syncthreads();                              // dump reads done before next tile
  }
}

// ---------------- dec tiles + pred units (direct-store epilogues) ----------------

__global__ __launch_bounds__(256, 2) void k_decpred(
    const _Float16* __restrict__ wt, const _Float16* __restrict__ pe_ws,
    const _Float16* __restrict__ pet0, const _Float16* __restrict__ mfull,
    const float* __restrict__ dec_b, const float* __restrict__ dec_bout,
    float* __restrict__ out1, float* __restrict__ out2, float* __restrict__ out3) {
  __shared__ char sm[LDSD];
  float* bl = (float*)(sm + 65536);
  int tid = threadIdx.x, lane = tid & 63;
  int r15 = lane & 15, hi = lane >> 4;
  int wbase = (tid >> 6) * 32;
  h8 B0[8], B1[8], B2[8], B3[8], B4[8];
  loadW(B0, wt + WT_DECW,           wbase, r15, hi);
  loadW(B1, wt + WT_DECW + 16384,   wbase, r15, hi);
  loadW(B2, wt + WT_DECW + 2*16384, wbase, r15, hi);
  loadW(B3, wt + WT_DECW + 3*16384, wbase, r15, hi);
  loadW(B4, wt + WT_DECWOUT,        wbase, r15, hi);
  PIN(B0); PIN(B1); PIN(B2); PIN(B3); PIN(B4);
  bl[tid] = dec_b[tid]; bl[256 + tid] = dec_b[256 + tid];
  if (tid < 128) bl[512 + tid] = dec_bout[tid];
  f4 acc[4][2];

  for (int u = blockIdx.x; u < NUNITS; u += gridDim.x) {
    __syncthreads();                              // protect h bufs across units
    if (u < NT64) {
      // ---------- dec tile: pe -> out2 ; pd = pe@comb -> dec -> out1 ----------
      const char* src = (const char*)pe_ws + (size_t)u*16384;
#pragma unroll
      for (int i = 0; i < 4; ++i) {               // stage pe -> H0 (input+skip)
        int off = (i*256 + tid)*16;
        *(f4*)(sm + H0 + off) = *(const f4*)(src + off);
      }
      __syncthreads();
      // stream B: dec(pe)
      LAYD(H0, H1, B0, 0); LAYD(H1, H2, B1, 128);
      LAYD(H2, H1, B2, 256); LAYD(H1, H2, B3, 384);
      mmF4s(sm, H2, B4, acc, r15, hi);            // decWout
      epi_direct(sm, H0, wbase, acc, bl,
                 out2 + (size_t)u*64*128, 128, r15, hi);   // no barrier
      {                                           // pd = pe @ comb (transient regs)
        h8 Bc[8];
        loadW(Bc, wt + WT_COMB, wbase, r15, hi);
        mmF4s(sm, H0, Bc, acc, r15, hi);
      }
      hw4r(sm, H3, wbase, acc, r15, hi);          // pd -> H3 (input+skip)
      __syncthreads();
      // stream A: dec(pd)
      LAYD(H3, H0, B0, 0); LAYD(H0, H1, B1, 128);
      LAYD(H1, H0, B2, 256); LAYD(H0, H1, B3, 384);
      mmF4s(sm, H1, B4, acc, r15, hi);            // decWout
      epi_direct(sm, H3, wbase, acc, bl,
                 out1 + (size_t)u*64*128, 128, r15, hi);   // no barrier
    } else {
      // ---------- pred unit: pet0 rtile x 2 Koopman steps ----------
      int p = u - NT64, rtile = p / 25, chunk = p % 25;
#pragma unroll
      for (int i = 0; i < 4; ++i) {               // stage pet0 -> H0 (persistent)
        int idx = i*256 + tid, rl = idx >> 4, c = idx & 15;
        f4 v = *(const f4*)((const char*)pet0 + (size_t)(rtile*64 + rl)*256 + c*16);
        *(f4*)(sm + H0 + hsw(rl, c)) = v;
      }
      __syncthreads();
      for (int s = chunk*2; s < chunk*2 + 2; ++s) {
        {
          h8 Bm[8];
          loadW(Bm, mfull + (size_t)s*16384, wbase, r15, hi);
          mmF4s(sm, H0, Bm, acc, r15, hi);        // di = pet0 @ Mfull_s
        }
        hw4r(sm, H1, wbase, acc, r15, hi);        // di -> H1 (input+skip)
        __syncthreads();
        LAYD(H1, H2, B0, 0); LAYD(H2, H3, B1, 128);
        LAYD(H3, H2, B2, 256); LAYD(H2, H3, B3, 384);
        mmF4s(sm, H3, B4, acc, r15, hi);          // decWout
        epi_direct(sm, H1, wbase, acc, bl,
                   out3 + ((size_t)rtile*64*50 + s)*128, 50*128, r15, hi);
        __syncthreads();                          // H1 skip reads done before next hw4r
      }
    }
  }
}

// ---------------- launch ----------------

extern "C" void kernel_launch(void* const* d_in, const int* in_sizes, int n_in,
                              void* d_out, int out_size, void* d_ws, size_t ws_size,
                              hipStream_t stream) {
  const float* x        = (const float*)d_in[0];
  const float* encW     = (const float*)d_in[1];
  const float* enc_b    = (const float*)d_in[2];
  const float* encWout  = (const float*)d_in[3];
  const float* enc_bout = (const float*)d_in[4];
  const float* decW     = (const float*)d_in[5];
  const float* dec_b    = (const float*)d_in[6];
  const float* decWout  = (const float*)d_in[7];
  const float* dec_bout = (const float*)d_in[8];
  const float* wencI    = (const float*)d_in[9];
  const float* L        = (const float*)d_in[10];
  const float* wdecI    = (const float*)d_in[11];

  char* ws = (char*)d_ws;
  _Float16* wt    = (_Float16*)ws;
  _Float16* mfull = (_Float16*)(ws + MFULL_OFF_B);
  float*    ach   = (float*)(ws + ACH_OFF_B);
  _Float16* pe_ws = (_Float16*)(ws + PE_OFF_B);
  _Float16* pet0  = (_Float16*)(ws + PET0_OFF_B);

  float* out1 = (float*)d_out;                       // autoencoder_output
  float* out2 = out1 + (size_t)ROWS_AUTO*128;        // outer_auto_output
  float* out3 = out2 + (size_t)ROWS_AUTO*128;        // predictions [2048][50][128]

  hipLaunchKernelGGL(k_prep, dim3(32, 11), dim3(512), 0, stream,
                     encW, encWout, decW, decWout, L, wt, ach);
  hipLaunchKernelGGL(k_aux, dim3(51), dim3(512), 0, stream,
                     ach, wencI, wdecI, mfull, wt);
  hipLaunchKernelGGL(k_enc, dim3(512), dim3(256), 0, stream,
                     x, wt, enc_b, enc_bout, pe_ws, pet0);
  hipLaunchKernelGGL(k_decpred, dim3(512), dim3(256), 0, stream,
                     wt, pe_ws, pet0, mfull, dec_b, dec_bout, out1, out2, out3);
}